// Round 12
// baseline (110.743 us; speedup 1.0000x reference)
//
#include <hip/hip_runtime.h>
#include <hip/hip_bf16.h>
#include <math.h>

#define BS 8
#define NN 1024
#define FIN 256
#define HEADS 8
#define FO 64
#define NH (HEADS*FO)   /* 512 */
static constexpr float ALPHA = 0.2f;
static constexpr float LOG2E = 1.4426950408889634f;

typedef short bf16x8 __attribute__((ext_vector_type(8)));
typedef float f32x4  __attribute__((ext_vector_type(4)));
typedef unsigned short u16;
typedef unsigned u32;
typedef u16 u16x4v __attribute__((ext_vector_type(4)));
typedef u16 u16x8v __attribute__((ext_vector_type(8)));

__device__ __forceinline__ u16 f2b(float x) {
    __hip_bfloat16 b = __float2bfloat16(x);
    return *reinterpret_cast<u16*>(&b);
}
__device__ __forceinline__ float fexp2(float x) {
#if __has_builtin(__builtin_amdgcn_exp2f)
    return __builtin_amdgcn_exp2f(x);
#else
    float r; asm("v_exp_f32 %0, %1" : "=v"(r) : "v"(x)); return r;
#endif
}
__device__ __forceinline__ void gload_lds16(const void* g, void* l) {
    __builtin_amdgcn_global_load_lds(
        (const __attribute__((address_space(1))) unsigned int*)g,
        (__attribute__((address_space(3))) unsigned int*)l, 16, 0, 0);
}

// ---------------------------------------------------------------------------
// prep_misc: fused {pack_adj | cvt_h | cvt_wT}. 8192 + 1024 + 32 blocks.
// ---------------------------------------------------------------------------
__global__ __launch_bounds__(256) void prep_misc(const float* __restrict__ h,
                                                 const int* __restrict__ adj,
                                                 const float* __restrict__ W,
                                                 u16* __restrict__ hb,
                                                 u16* __restrict__ WbT,
                                                 u32* __restrict__ bits) {
    const int bid = blockIdx.x;
    const int t = threadIdx.x;
    if (bid < 8192) {
        const int lane = t & 63;
        const size_t e0 = ((size_t)bid * 256 + t) * 4;
        const int4 v = *reinterpret_cast<const int4*>(adj + e0);
        u32 x = (v.x ? 1u : 0u) | (v.y ? 2u : 0u) | (v.z ? 4u : 0u) | (v.w ? 8u : 0u);
        {   const u32 r = (u32)__shfl_xor((int)x, 1);
            const int sh = (lane & 1) * 4;  x = (x << sh) | (r << (4 - sh)); }
        {   const u32 r = (u32)__shfl_xor((int)x, 2);
            const int sh = (lane & 2) * 4;  x = (x << sh) | (r << (8 - sh)); }
        {   const u32 r = (u32)__shfl_xor((int)x, 4);
            const int sh = (lane & 4) * 4;  x = (x << sh) | (r << (16 - sh)); }
        if ((lane & 7) == 0) bits[e0 >> 5] = x;
    } else if (bid < 9216) {
        const int i = ((bid - 8192) * 256 + t) * 8;
        const float4 v0 = *reinterpret_cast<const float4*>(h + i);
        const float4 v1 = *reinterpret_cast<const float4*>(h + i + 4);
        u16x8v o;
        o[0]=f2b(v0.x); o[1]=f2b(v0.y); o[2]=f2b(v0.z); o[3]=f2b(v0.w);
        o[4]=f2b(v1.x); o[5]=f2b(v1.y); o[6]=f2b(v1.z); o[7]=f2b(v1.w);
        *reinterpret_cast<u16x8v*>(hb + i) = o;
    } else {
        __shared__ float T[64][65];
        const int bb = bid - 9216;
        const int hh = bb & 7;
        const int n0 = hh * 64, k0 = (bb >> 3) * 64;
        const int r4 = t >> 6, c = t & 63;
        #pragma unroll
        for (int p = 0; p < 16; ++p) {
            const int r = p * 4 + r4;
            T[r][c] = W[(size_t)(k0 + r) * NH + n0 + c];
        }
        __syncthreads();
        #pragma unroll
        for (int p = 0; p < 16; ++p) {
            const int r = p * 4 + r4;
            WbT[(size_t)(n0 + r) * FIN + k0 + c] = f2b(T[c][r]);
        }
    }
}

// ---------------------------------------------------------------------------
// gemm_whT: Wh = hb @ WbT^T, 64x64 tile, grid 1024, XCD-chunked.
// Epilogue: exact-f32 e_src/e_dst from accumulators + transposed bf16 WhT.
// ---------------------------------------------------------------------------
__global__ __launch_bounds__(256) void gemm_whT(const u16* __restrict__ hb,
                                                const u16* __restrict__ WbT,
                                                const float* __restrict__ avec,
                                                u16* __restrict__ WhT,
                                                float* __restrict__ esrc,
                                                float* __restrict__ edst) {
    __shared__ u16 Al[2][64 * 64];
    __shared__ u16 Bl[2][64 * 64];
    const int t = threadIdx.x, wv = t >> 6, lane = t & 63;
    const int g = lane >> 4, l15 = lane & 15;
    const int lid = (blockIdx.x & 7) * 128 + (blockIdx.x >> 3);
    const int m0 = (lid >> 3) * 64;
    const int h  = lid & 7;
    const int lr = lane >> 3;
    const int sch = (lane & 7) ^ lr;
    const int bh = (m0 >> 10) * HEADS + h;

    f32x4 acc[4] = {};

    auto stageA = [&](int buf, int k0) {
        #pragma unroll
        for (int c = 0; c < 2; ++c) {
            const int rowb = wv * 16 + c * 8;
            gload_lds16(hb + (size_t)(m0 + rowb + lr) * FIN + k0 + sch * 8,
                        &Al[buf][rowb * 64]);
        }
    };
    auto stageB = [&](int buf, int k0) {
        #pragma unroll
        for (int c = 0; c < 2; ++c) {
            const int rowb = wv * 16 + c * 8;
            gload_lds16(WbT + (size_t)(h * 64 + rowb + lr) * FIN + k0 + sch * 8,
                        &Bl[buf][rowb * 64]);
        }
    };

    stageA(0, 0); stageB(0, 0);
    __syncthreads();
    for (int kt = 0; kt < 4; ++kt) {
        const int buf = kt & 1;
        if (kt < 3) { stageA(buf ^ 1, (kt + 1) * 64); stageB(buf ^ 1, (kt + 1) * 64); }
        #pragma unroll
        for (int ks = 0; ks < 2; ++ks) {
            const int ch = (ks * 4 + g) ^ (l15 & 7);
            const bf16x8 afr = *reinterpret_cast<const bf16x8*>(
                &Al[buf][(wv * 16 + l15) * 64 + ch * 8]);
            #pragma unroll
            for (int n = 0; n < 4; ++n) {
                const bf16x8 bfr = *reinterpret_cast<const bf16x8*>(
                    &Bl[buf][(n * 16 + l15) * 64 + ch * 8]);
                acc[n] = __builtin_amdgcn_mfma_f32_16x16x32_bf16(afr, bfr, acc[n], 0, 0, 0);
            }
        }
        __syncthreads();
    }

    // ---- e epilogue (exact f32, exp2 domain) ----
    {
        float as_[4], ad_[4];
        #pragma unroll
        for (int n = 0; n < 4; ++n) {
            as_[n] = avec[h * 128 + n * 16 + l15] * LOG2E;
            ad_[n] = avec[h * 128 + 64 + n * 16 + l15] * LOG2E;
        }
        #pragma unroll
        for (int r = 0; r < 4; ++r) {
            float ps = acc[0][r] * as_[0] + acc[1][r] * as_[1]
                     + acc[2][r] * as_[2] + acc[3][r] * as_[3];
            float pd = acc[0][r] * ad_[0] + acc[1][r] * ad_[1]
                     + acc[2][r] * ad_[2] + acc[3][r] * ad_[3];
            #pragma unroll
            for (int off = 1; off < 16; off <<= 1) {
                ps += __shfl_xor(ps, off);
                pd += __shfl_xor(pd, off);
            }
            if (l15 == 0) {
                const int i = (m0 + wv * 16 + g * 4 + r) & (NN - 1);
                esrc[(size_t)bh * NN + i] = ps;
                edst[(size_t)bh * NN + i] = pd;
            }
        }
    }

    // ---- WhT store via LDS bounce (coalesced) ----
    u16* scr = &Al[0][0];
    #pragma unroll
    for (int n = 0; n < 4; ++n) {
        u16x4v pk;
        #pragma unroll
        for (int r = 0; r < 4; ++r) pk[r] = f2b(acc[n][r]);
        *reinterpret_cast<u16x4v*>(&scr[(n * 16 + l15) * 72 + wv * 16 + g * 4]) = pk;
    }
    __syncthreads();
    const int il0 = m0 & (NN - 1);
    const int f = t >> 2, q = t & 3;
    const u16x8v v0 = *reinterpret_cast<const u16x8v*>(&scr[f * 72 + q * 16]);
    const u16x8v v1 = *reinterpret_cast<const u16x8v*>(&scr[f * 72 + q * 16 + 8]);
    u16* dst = &WhT[((size_t)bh * 64 + f) * NN + il0 + q * 16];
    *reinterpret_cast<u16x8v*>(dst)     = v0;
    *reinterpret_cast<u16x8v*>(dst + 8) = v1;
}

// ---------------------------------------------------------------------------
// attn_pv v7: per-head waves, wave-private V dbuf, ZERO in-loop barriers.
// Block = 4 waves = 4 heads x same 16 i-rows; grid 1024 -> 4 blocks/CU
// (4 waves/SIMD). Each wave stages its own 32-j V tile (4 KB) via
// global_load_lds; tile sync = wave-local counted s_waitcnt vmcnt(6).
// bitsT shared in LDS (one __syncthreads total). dsum via mfma(P, ones).
// ---------------------------------------------------------------------------
__global__ __launch_bounds__(256, 4) void attn_pv(const u32* __restrict__ bits,
                                                  const u16* __restrict__ WhT,
                                                  const float* __restrict__ esrc,
                                                  const float* __restrict__ edst,
                                                  float* __restrict__ out) {
    __shared__ u16 Vb[4][2][2048];            // [wave][buf][32j x 64f] = 4KB each
    __shared__ u32 bitsT[32][16];             // [word][row], 2KB

    const int t = threadIdx.x, wv = t >> 6, lane = t & 63;
    const int g = lane >> 4, l15 = lane & 15;

    // XCD chunk: 128 consecutive lids per XCD -> 2 (b,head-group) combos/XCD
    const int lid = (blockIdx.x & 7) * 128 + (blockIdx.x >> 3);
    const int it = lid & 63;                  // i-chunk 0..63
    const int combo = lid >> 6;               // 0..15
    const int b = combo >> 1, hg = combo & 1;
    const int i0 = it * 16;
    const int h  = hg * 4 + wv;
    const int bh = b * HEADS + h;

    const float es = esrc[(size_t)bh * NN + i0 + l15];   // row = l15
    const u16*  whb = WhT + (size_t)bh * 64 * NN;
    const float* ed = edst + (size_t)bh * NN + 8 * g;

    // stage one 32-j tile of this wave's head: 4 gloads x 1KB
    // LDS[f][slot] linear; source pre-swizzled: jc = slot ^ ((f>>1)&3)
    auto stage = [&](int buf, int j0) {
        const int fr  = lane >> 2;                       // f row within 16-group
        const int jc  = (lane & 3) ^ ((lane >> 3) & 3);  // swizzled j-chunk
        #pragma unroll
        for (int c = 0; c < 4; ++c) {
            gload_lds16(whb + (size_t)(c * 16 + fr) * NN + j0 + jc * 8,
                        &Vb[wv][buf][c * 512]);
        }
    };

    // ---- prologue ----
    {   // bitsT: 2 words per thread, rows shared by all 4 waves
        const int r = t & 15, w2 = t >> 4;               // w2 = 0..15
        const u32* src = bits + (size_t)(b * NN + i0 + r) * 32 + w2 * 2;
        bitsT[w2 * 2 + 0][r] = src[0];
        bitsT[w2 * 2 + 1][r] = src[1];
    }
    stage(0, 0);
    float4 peA[2], peB[2];
    #pragma unroll
    for (int s = 0; s < 2; ++s) {
        peA[s] = *(const float4*)(ed + s * 32);
        peB[s] = *(const float4*)(ed + s * 32 + 4);
    }
    __syncthreads();                                     // bitsT ready (only barrier)
    u32 pw = bitsT[0][l15];

    // hoisted per-lane LDS read base (bytes within a 4KB tile)
    const int bsB = l15 * 64 + ((g ^ ((l15 >> 1) & 3)) << 4);
    const char* vwave = (const char*)&Vb[wv][0][0];

    f32x4 acc[4] = {};
    f32x4 dsum = {};
    bf16x8 ones;
    #pragma unroll
    for (int q = 0; q < 8; ++q) ones[q] = (short)0x3F80; // bf16(1.0)

    for (int tt = 0; tt < 32; ++tt) {
        const int buf = tt & 1;
        // uniform issue (clamped indices; over-issues are never consumed)
        const int jn = (tt < 31) ? (tt + 1) * 32 : 31 * 32;
        const int en = (tt < 30) ? (tt + 2) * 32 : 31 * 32;
        stage(buf ^ 1, jn);
        asm volatile("" ::: "memory");        // pin: ed loads stay after stage
        const float4 e0 = peA[buf], e1 = peB[buf];
        const u32 word = pw;
        peA[buf] = *(const float4*)(ed + en);
        peB[buf] = *(const float4*)(ed + en + 4);
        pw = bitsT[(tt < 31) ? tt + 1 : 31][l15];
        // wave-local tile sync: 4 stage + 2 ed just issued stay in flight
        asm volatile("s_waitcnt vmcnt(6)" ::: "memory");

        const char* vb = vwave + buf * 4096 + bsB;
        const bf16x8 v0 = *(const bf16x8*)(vb);
        const bf16x8 v1 = *(const bf16x8*)(vb + 1024);
        const bf16x8 v2 = *(const bf16x8*)(vb + 2048);
        const bf16x8 v3 = *(const bf16x8*)(vb + 3072);

        const u32 byte_ = (word >> (8 * g)) & 0xffu;
        float ps[8];
        {
            float sv;
            sv = es + e0.x; sv = fmaxf(sv, ALPHA * sv); sv = (byte_ & 1u)        ? sv : -1e30f; ps[0] = fexp2(sv);
            sv = es + e0.y; sv = fmaxf(sv, ALPHA * sv); sv = ((byte_ >> 1) & 1u) ? sv : -1e30f; ps[1] = fexp2(sv);
            sv = es + e0.z; sv = fmaxf(sv, ALPHA * sv); sv = ((byte_ >> 2) & 1u) ? sv : -1e30f; ps[2] = fexp2(sv);
            sv = es + e0.w; sv = fmaxf(sv, ALPHA * sv); sv = ((byte_ >> 3) & 1u) ? sv : -1e30f; ps[3] = fexp2(sv);
            sv = es + e1.x; sv = fmaxf(sv, ALPHA * sv); sv = ((byte_ >> 4) & 1u) ? sv : -1e30f; ps[4] = fexp2(sv);
            sv = es + e1.y; sv = fmaxf(sv, ALPHA * sv); sv = ((byte_ >> 5) & 1u) ? sv : -1e30f; ps[5] = fexp2(sv);
            sv = es + e1.z; sv = fmaxf(sv, ALPHA * sv); sv = ((byte_ >> 6) & 1u) ? sv : -1e30f; ps[6] = fexp2(sv);
            sv = es + e1.w; sv = fmaxf(sv, ALPHA * sv); sv = ((byte_ >> 7) & 1u) ? sv : -1e30f; ps[7] = fexp2(sv);
        }
        union { u32 u[4]; bf16x8 v; } af;
        #pragma unroll
        for (int qp = 0; qp < 4; ++qp) {
            union { __hip_bfloat162 b2; u32 w; } cv;
            cv.b2 = __float22bfloat162_rn(make_float2(ps[2*qp], ps[2*qp+1]));
            af.u[qp] = cv.w;
        }
        __builtin_amdgcn_s_setprio(1);
        acc[0] = __builtin_amdgcn_mfma_f32_16x16x32_bf16(af.v, v0, acc[0], 0, 0, 0);
        acc[1] = __builtin_amdgcn_mfma_f32_16x16x32_bf16(af.v, v1, acc[1], 0, 0, 0);
        acc[2] = __builtin_amdgcn_mfma_f32_16x16x32_bf16(af.v, v2, acc[2], 0, 0, 0);
        acc[3] = __builtin_amdgcn_mfma_f32_16x16x32_bf16(af.v, v3, acc[3], 0, 0, 0);
        dsum   = __builtin_amdgcn_mfma_f32_16x16x32_bf16(af.v, ones, dsum, 0, 0, 0);
        __builtin_amdgcn_s_setprio(0);
    }

    float inv[4];
    #pragma unroll
    for (int r = 0; r < 4; ++r) inv[r] = 1.0f / dsum[r];
    #pragma unroll
    for (int n = 0; n < 4; ++n)
        #pragma unroll
        for (int r = 0; r < 4; ++r) {
            const int io = i0 + g * 4 + r;
            out[(size_t)(b * NN + io) * NH + h * 64 + n * 16 + l15] =
                acc[n][r] * inv[r];
        }
}

// ---------------------------------------------------------------------------
extern "C" void kernel_launch(void* const* d_in, const int* in_sizes, int n_in,
                              void* d_out, int out_size, void* d_ws, size_t ws_size,
                              hipStream_t stream) {
    const float* h   = (const float*)d_in[0];
    const int*   adj = (const int*)  d_in[1];
    const float* W   = (const float*)d_in[2];
    const float* a   = (const float*)d_in[3];
    float* out = (float*)d_out;

    char* p = (char*)d_ws;
    u16*   hb   = (u16*)p;   p += (size_t)BS * NN * FIN * 2;        // 4 MB
    u16*   WbT  = (u16*)p;   p += (size_t)NH * FIN * 2;             // 256 KB
    u16*   WhT  = (u16*)p;   p += (size_t)BS * HEADS * FO * NN * 2; // 8 MB
    float* esrc = (float*)p; p += (size_t)BS * HEADS * NN * 4;      // 256 KB
    float* edst = (float*)p; p += (size_t)BS * HEADS * NN * 4;      // 256 KB
    u32*   bits = (u32*)p;                                          // 1 MB

    prep_misc<<<9248, 256, 0, stream>>>(h, adj, W, hb, WbT, bits);
    gemm_whT <<<1024, 256, 0, stream>>>(hb, WbT, a, WhT, esrc, edst);
    attn_pv  <<<1024, 256, 0, stream>>>(bits, WhT, esrc, edst, out);
}

// Round 13
// 65.324 us; speedup vs baseline: 1.6953x; 1.6953x over previous
//
#include <hip/hip_runtime.h>
#include <hip/hip_bf16.h>
#include <math.h>

#define BS 8
#define NN 1024
#define FIN 256
#define HEADS 8
#define FO 64
#define NH (HEADS*FO)   /* 512 */
static constexpr float ALPHA = 0.2f;
static constexpr float LOG2E = 1.4426950408889634f;

typedef short bf16x8 __attribute__((ext_vector_type(8)));
typedef float f32x4  __attribute__((ext_vector_type(4)));
typedef unsigned short u16;
typedef unsigned u32;
typedef u16 u16x4v __attribute__((ext_vector_type(4)));
typedef u16 u16x8v __attribute__((ext_vector_type(8)));

__device__ __forceinline__ u16 f2b(float x) {
    __hip_bfloat16 b = __float2bfloat16(x);
    return *reinterpret_cast<u16*>(&b);
}
__device__ __forceinline__ float fexp2(float x) {
#if __has_builtin(__builtin_amdgcn_exp2f)
    return __builtin_amdgcn_exp2f(x);
#else
    float r; asm("v_exp_f32 %0, %1" : "=v"(r) : "v"(x)); return r;
#endif
}
__device__ __forceinline__ void gload_lds16(const void* g, void* l) {
    __builtin_amdgcn_global_load_lds(
        (const __attribute__((address_space(1))) unsigned int*)g,
        (__attribute__((address_space(3))) unsigned int*)l, 16, 0, 0);
}

// ---------------------------------------------------------------------------
// prep_misc: fused {pack_adj | cvt_h | cvt_wT}. 8192 + 1024 + 32 blocks.
// ---------------------------------------------------------------------------
__global__ __launch_bounds__(256) void prep_misc(const float* __restrict__ h,
                                                 const int* __restrict__ adj,
                                                 const float* __restrict__ W,
                                                 u16* __restrict__ hb,
                                                 u16* __restrict__ WbT,
                                                 u32* __restrict__ bits) {
    const int bid = blockIdx.x;
    const int t = threadIdx.x;
    if (bid < 8192) {
        const int lane = t & 63;
        const size_t e0 = ((size_t)bid * 256 + t) * 4;
        const int4 v = *reinterpret_cast<const int4*>(adj + e0);
        u32 x = (v.x ? 1u : 0u) | (v.y ? 2u : 0u) | (v.z ? 4u : 0u) | (v.w ? 8u : 0u);
        {   const u32 r = (u32)__shfl_xor((int)x, 1);
            const int sh = (lane & 1) * 4;  x = (x << sh) | (r << (4 - sh)); }
        {   const u32 r = (u32)__shfl_xor((int)x, 2);
            const int sh = (lane & 2) * 4;  x = (x << sh) | (r << (8 - sh)); }
        {   const u32 r = (u32)__shfl_xor((int)x, 4);
            const int sh = (lane & 4) * 4;  x = (x << sh) | (r << (16 - sh)); }
        if ((lane & 7) == 0) bits[e0 >> 5] = x;
    } else if (bid < 9216) {
        const int i = ((bid - 8192) * 256 + t) * 8;
        const float4 v0 = *reinterpret_cast<const float4*>(h + i);
        const float4 v1 = *reinterpret_cast<const float4*>(h + i + 4);
        u16x8v o;
        o[0]=f2b(v0.x); o[1]=f2b(v0.y); o[2]=f2b(v0.z); o[3]=f2b(v0.w);
        o[4]=f2b(v1.x); o[5]=f2b(v1.y); o[6]=f2b(v1.z); o[7]=f2b(v1.w);
        *reinterpret_cast<u16x8v*>(hb + i) = o;
    } else {
        __shared__ float T[64][65];
        const int bb = bid - 9216;
        const int hh = bb & 7;
        const int n0 = hh * 64, k0 = (bb >> 3) * 64;
        const int r4 = t >> 6, c = t & 63;
        #pragma unroll
        for (int p = 0; p < 16; ++p) {
            const int r = p * 4 + r4;
            T[r][c] = W[(size_t)(k0 + r) * NH + n0 + c];
        }
        __syncthreads();
        #pragma unroll
        for (int p = 0; p < 16; ++p) {
            const int r = p * 4 + r4;
            WbT[(size_t)(n0 + r) * FIN + k0 + c] = f2b(T[c][r]);
        }
    }
}

// ---------------------------------------------------------------------------
// gemm_whT: Wh = hb @ WbT^T, 128x128 tile (m93/m97 ladder), grid 256,
// 4 waves as 2m x 2n (each wave = 64 rows x one full head's 64 cols).
// Epilogue: exact-f32 e_src/e_dst from accumulators + transposed bf16 WhT.
// ---------------------------------------------------------------------------
__global__ __launch_bounds__(256) void gemm_whT(const u16* __restrict__ hb,
                                                const u16* __restrict__ WbT,
                                                const float* __restrict__ avec,
                                                u16* __restrict__ WhT,
                                                float* __restrict__ esrc,
                                                float* __restrict__ edst) {
    __shared__ u16 Al[2][128 * 64];   // 32 KB
    __shared__ u16 Bl[2][128 * 64];   // 32 KB
    const int t = threadIdx.x, wv = t >> 6, lane = t & 63;
    const int g = lane >> 4, l15 = lane & 15;
    const int lr = lane >> 3;
    const int sch = (lane & 7) ^ lr;

    // XCD chunk: 4 consecutive lids share the A panel (same m-tile)
    const int lid = (blockIdx.x & 7) * 32 + (blockIdx.x >> 3);
    const int mt = lid >> 2, nt = lid & 3;
    const int m0 = mt * 128;
    const int b  = mt >> 3;
    const int il0 = (mt & 7) * 128;
    const int wm = wv >> 1, wn = wv & 1;
    const int head = nt * 2 + wn;
    const int bh = b * HEADS + head;

    f32x4 acc[4][4] = {};

    auto stageA = [&](int buf, int k0) {
        #pragma unroll
        for (int c = 0; c < 4; ++c) {
            const int rowb = wv * 32 + c * 8;
            gload_lds16(hb + (size_t)(m0 + rowb + lr) * FIN + k0 + sch * 8,
                        &Al[buf][rowb * 64]);
        }
    };
    auto stageB = [&](int buf, int k0) {
        #pragma unroll
        for (int c = 0; c < 4; ++c) {
            const int rowb = wv * 32 + c * 8;
            gload_lds16(WbT + (size_t)(nt * 128 + rowb + lr) * FIN + k0 + sch * 8,
                        &Bl[buf][rowb * 64]);
        }
    };

    stageA(0, 0); stageB(0, 0);
    __syncthreads();
    for (int kt = 0; kt < 4; ++kt) {
        const int buf = kt & 1;
        if (kt < 3) { stageA(buf ^ 1, (kt + 1) * 64); stageB(buf ^ 1, (kt + 1) * 64); }
        #pragma unroll
        for (int ks = 0; ks < 2; ++ks) {
            const int ch = (ks * 4 + g) ^ (l15 & 7);
            bf16x8 af[4], bf[4];
            #pragma unroll
            for (int mf = 0; mf < 4; ++mf)
                af[mf] = *reinterpret_cast<const bf16x8*>(
                    &Al[buf][(wm * 64 + mf * 16 + l15) * 64 + ch * 8]);
            #pragma unroll
            for (int n = 0; n < 4; ++n)
                bf[n] = *reinterpret_cast<const bf16x8*>(
                    &Bl[buf][(wn * 64 + n * 16 + l15) * 64 + ch * 8]);
            #pragma unroll
            for (int mf = 0; mf < 4; ++mf)
                #pragma unroll
                for (int n = 0; n < 4; ++n)
                    acc[mf][n] = __builtin_amdgcn_mfma_f32_16x16x32_bf16(
                        af[mf], bf[n], acc[mf][n], 0, 0, 0);
        }
        __syncthreads();
    }

    // ---- e epilogue (exact f32, exp2 domain) ----
    {
        float as_[4], ad_[4];
        #pragma unroll
        for (int n = 0; n < 4; ++n) {
            as_[n] = avec[head * 128 + n * 16 + l15] * LOG2E;
            ad_[n] = avec[head * 128 + 64 + n * 16 + l15] * LOG2E;
        }
        #pragma unroll
        for (int mf = 0; mf < 4; ++mf)
            #pragma unroll
            for (int r = 0; r < 4; ++r) {
                float ps = acc[mf][0][r] * as_[0] + acc[mf][1][r] * as_[1]
                         + acc[mf][2][r] * as_[2] + acc[mf][3][r] * as_[3];
                float pd = acc[mf][0][r] * ad_[0] + acc[mf][1][r] * ad_[1]
                         + acc[mf][2][r] * ad_[2] + acc[mf][3][r] * ad_[3];
                #pragma unroll
                for (int off = 1; off < 16; off <<= 1) {
                    ps += __shfl_xor(ps, off);
                    pd += __shfl_xor(pd, off);
                }
                if (l15 == 0) {
                    const int i = il0 + wm * 64 + mf * 16 + g * 4 + r;
                    esrc[(size_t)bh * NN + i] = ps;
                    edst[(size_t)bh * NN + i] = pd;
                }
            }
    }

    // ---- WhT store via LDS bounce: head wn=0 -> Al scratch, wn=1 -> Bl ----
    u16* scrH = wn ? &Bl[0][0] : &Al[0][0];    // 64 f x 132 i pad = 16.9 KB
    #pragma unroll
    for (int mf = 0; mf < 4; ++mf)
        #pragma unroll
        for (int n = 0; n < 4; ++n) {
            u16x4v pk;
            #pragma unroll
            for (int r = 0; r < 4; ++r) pk[r] = f2b(acc[mf][n][r]);
            *reinterpret_cast<u16x4v*>(
                &scrH[(n * 16 + l15) * 132 + wm * 64 + mf * 16 + g * 4]) = pk;
        }
    __syncthreads();
    {
        const int hsel = t >> 7;               // 0: Al, 1: Bl (uniform per wave)
        const int f    = (t >> 1) & 63;
        const int seg  = t & 1;
        const u16* src = (hsel ? &Bl[0][0] : &Al[0][0]) + f * 132 + seg * 64;
        u16* dst = &WhT[((size_t)(b * HEADS + nt * 2 + hsel) * 64 + f) * NN
                        + il0 + seg * 64];
        #pragma unroll
        for (int k = 0; k < 8; ++k)
            *reinterpret_cast<u16x8v*>(dst + k * 8) =
                *reinterpret_cast<const u16x8v*>(src + k * 8);
    }
}

// ---------------------------------------------------------------------------
// attn_pv v9: r10 base (128 thr / 2 waves / 16 rows/wave, shared 64jx64f V,
// grid 2048) + 3-buffer 2-tiles-ahead staging (stage stall eliminated),
// uniform clamped issues -> exact counted vmcnt(16), setprio, dsum via MFMA.
// ---------------------------------------------------------------------------
__global__ __launch_bounds__(128, 3) void attn_pv(const u32* __restrict__ bits,
                                                  const u16* __restrict__ WhT,
                                                  const float* __restrict__ esrc,
                                                  const float* __restrict__ edst,
                                                  float* __restrict__ out) {
    __shared__ u16 Bs[3][64 * 64];             // 24 KB: 3-deep V tile ring
    const int t = threadIdx.x, wv = t >> 6, lane = t & 63;
    const int g = lane >> 4, l15 = lane & 15;
    const int lr = lane >> 3, sch = (lane & 7) ^ lr;

    // XCD chunk: 256 consecutive lids (one batch) per XCD
    const int lid = (blockIdx.x & 7) * 256 + (blockIdx.x >> 3);
    const int it = lid & 31, h = (lid >> 5) & 7, b = lid >> 8;
    const int i0 = it * 32;
    const int bh = b * HEADS + h;
    const int rowi = i0 + wv * 16 + l15;

    const float es = esrc[(size_t)bh * NN + rowi];
    const u16*  whb = WhT + (size_t)bh * 64 * NN;
    const float* ed = edst + (size_t)bh * NN + 8 * g;
    const u32*  bitrow = bits + (size_t)(b * NN + rowi) * 32;

    auto stage = [&](int buf, int j0) {
        #pragma unroll
        for (int c = 0; c < 4; ++c) {
            const int fb = wv * 32 + c * 8;
            gload_lds16(whb + (size_t)(fb + lr) * NN + j0 + sch * 8,
                        &Bs[buf][fb * 64]);
        }
    };

    // ---- prologue: stage tiles 0,1; prefetch steps 0,1 ----
    stage(0, 0);
    stage(1, 64);
    float4 peA[2], peB[2];
    u32    pwS[2];
    #pragma unroll
    for (int s = 0; s < 2; ++s) {
        peA[s] = *(const float4*)(ed + s * 32);
        peB[s] = *(const float4*)(ed + s * 32 + 4);
        pwS[s] = bitrow[s];
    }
    // stage(0) done: newer = stage(1) 4 + prefetch 6 = 10
    asm volatile("s_waitcnt vmcnt(10)" ::: "memory");
    __builtin_amdgcn_s_barrier();

    f32x4 acc[4] = {};
    f32x4 dsum = {};
    bf16x8 ones;
    #pragma unroll
    for (int q = 0; q < 8; ++q) ones[q] = (short)0x3F80;   // bf16(1.0)

    int bufR = 0, bufW = 2;
    for (int tt = 0; tt < 16; ++tt) {
        // stage tile tt+2 (clamped; over-issues write an unused buffer)
        const int jn = (tt < 14) ? (tt + 2) * 64 : 15 * 64;
        stage(bufW, jn);
        asm volatile("" ::: "memory");         // pin: prefetches after stage
        const int bsBase = bufR * 8192;        // bytes
        #pragma unroll
        for (int ks = 0; ks < 2; ++ks) {
            const int s = tt * 2 + ks;
            const float4 e0 = peA[ks], e1 = peB[ks];
            const u32 word = pwS[ks];
            {   // refill slot with step s+2 (clamped -> uniform issue count)
                const int sn = (s < 30) ? s + 2 : 31;
                peA[ks] = *(const float4*)(ed + sn * 32);
                peB[ks] = *(const float4*)(ed + sn * 32 + 4);
                pwS[ks] = bitrow[sn];
            }
            // B fragments
            const char* bsb = (const char*)Bs + bsBase
                            + l15 * 128 + (((ks * 4 + g) ^ (l15 & 7)) << 4);
            const bf16x8 v0 = *(const bf16x8*)(bsb);
            const bf16x8 v1 = *(const bf16x8*)(bsb + 2048);
            const bf16x8 v2 = *(const bf16x8*)(bsb + 4096);
            const bf16x8 v3 = *(const bf16x8*)(bsb + 6144);

            const u32 byte_ = (word >> (8 * g)) & 0xffu;
            float ps[8];
            {
                float sv;
                sv = es + e0.x; sv = fmaxf(sv, ALPHA * sv); sv = (byte_ & 1u)        ? sv : -1e30f; ps[0] = fexp2(sv);
                sv = es + e0.y; sv = fmaxf(sv, ALPHA * sv); sv = ((byte_ >> 1) & 1u) ? sv : -1e30f; ps[1] = fexp2(sv);
                sv = es + e0.z; sv = fmaxf(sv, ALPHA * sv); sv = ((byte_ >> 2) & 1u) ? sv : -1e30f; ps[2] = fexp2(sv);
                sv = es + e0.w; sv = fmaxf(sv, ALPHA * sv); sv = ((byte_ >> 3) & 1u) ? sv : -1e30f; ps[3] = fexp2(sv);
                sv = es + e1.x; sv = fmaxf(sv, ALPHA * sv); sv = ((byte_ >> 4) & 1u) ? sv : -1e30f; ps[4] = fexp2(sv);
                sv = es + e1.y; sv = fmaxf(sv, ALPHA * sv); sv = ((byte_ >> 5) & 1u) ? sv : -1e30f; ps[5] = fexp2(sv);
                sv = es + e1.z; sv = fmaxf(sv, ALPHA * sv); sv = ((byte_ >> 6) & 1u) ? sv : -1e30f; ps[6] = fexp2(sv);
                sv = es + e1.w; sv = fmaxf(sv, ALPHA * sv); sv = ((byte_ >> 7) & 1u) ? sv : -1e30f; ps[7] = fexp2(sv);
            }
            union { u32 u[4]; bf16x8 v; } af;
            #pragma unroll
            for (int qp = 0; qp < 4; ++qp) {
                union { __hip_bfloat162 b2; u32 w; } cv;
                cv.b2 = __float22bfloat162_rn(make_float2(ps[2*qp], ps[2*qp+1]));
                af.u[qp] = cv.w;
            }
            __builtin_amdgcn_s_setprio(1);
            acc[0] = __builtin_amdgcn_mfma_f32_16x16x32_bf16(af.v, v0, acc[0], 0, 0, 0);
            acc[1] = __builtin_amdgcn_mfma_f32_16x16x32_bf16(af.v, v1, acc[1], 0, 0, 0);
            acc[2] = __builtin_amdgcn_mfma_f32_16x16x32_bf16(af.v, v2, acc[2], 0, 0, 0);
            acc[3] = __builtin_amdgcn_mfma_f32_16x16x32_bf16(af.v, v3, acc[3], 0, 0, 0);
            dsum   = __builtin_amdgcn_mfma_f32_16x16x32_bf16(af.v, ones, dsum, 0, 0, 0);
            __builtin_amdgcn_s_setprio(0);
        }
        if (tt < 15) {
            // need stage(tt+1) (issued 2 tiles back) done; newer VMEM:
            // pf(tt-1) 6 + stage(tt+2) 4 + pf(tt) 6 = 16 -> vmcnt(16)
            asm volatile("s_waitcnt vmcnt(16)" ::: "memory");
            __builtin_amdgcn_s_barrier();
        }
        bufR = (bufR == 2) ? 0 : bufR + 1;
        bufW = (bufW == 2) ? 0 : bufW + 1;
    }

    float inv[4];
    #pragma unroll
    for (int r = 0; r < 4; ++r) inv[r] = 1.0f / dsum[r];
    #pragma unroll
    for (int n = 0; n < 4; ++n)
        #pragma unroll
        for (int r = 0; r < 4; ++r) {
            const int io = i0 + wv * 16 + g * 4 + r;
            out[(size_t)(b * NN + io) * NH + h * 64 + n * 16 + l15] =
                acc[n][r] * inv[r];
        }
}

// ---------------------------------------------------------------------------
extern "C" void kernel_launch(void* const* d_in, const int* in_sizes, int n_in,
                              void* d_out, int out_size, void* d_ws, size_t ws_size,
                              hipStream_t stream) {
    const float* h   = (const float*)d_in[0];
    const int*   adj = (const int*)  d_in[1];
    const float* W   = (const float*)d_in[2];
    const float* a   = (const float*)d_in[3];
    float* out = (float*)d_out;

    char* p = (char*)d_ws;
    u16*   hb   = (u16*)p;   p += (size_t)BS * NN * FIN * 2;        // 4 MB
    u16*   WbT  = (u16*)p;   p += (size_t)NH * FIN * 2;             // 256 KB
    u16*   WhT  = (u16*)p;   p += (size_t)BS * HEADS * FO * NN * 2; // 8 MB
    float* esrc = (float*)p; p += (size_t)BS * HEADS * NN * 4;      // 256 KB
    float* edst = (float*)p; p += (size_t)BS * HEADS * NN * 4;      // 256 KB
    u32*   bits = (u32*)p;                                          // 1 MB

    prep_misc<<<9248, 256, 0, stream>>>(h, adj, W, hb, WbT, bits);
    gemm_whT <<<256, 256, 0, stream>>>(hb, WbT, a, WhT, esrc, edst);
    attn_pv  <<<2048, 128, 0, stream>>>(bits, WhT, esrc, edst, out);
}

// Round 14
// 56.637 us; speedup vs baseline: 1.9553x; 1.1534x over previous
//
#include <hip/hip_runtime.h>
#include <hip/hip_bf16.h>
#include <math.h>

#define BS 8
#define NN 1024
#define FIN 256
#define HEADS 8
#define FO 64
#define NH (HEADS*FO)   /* 512 */
static constexpr float ALPHA = 0.2f;
static constexpr float LOG2E = 1.4426950408889634f;

typedef short bf16x8 __attribute__((ext_vector_type(8)));
typedef float f32x4  __attribute__((ext_vector_type(4)));
typedef unsigned short u16;
typedef unsigned u32;
typedef u16 u16x4v __attribute__((ext_vector_type(4)));
typedef u16 u16x8v __attribute__((ext_vector_type(8)));

__device__ __forceinline__ u16 f2b(float x) {
    __hip_bfloat16 b = __float2bfloat16(x);
    return *reinterpret_cast<u16*>(&b);
}
__device__ __forceinline__ float fexp2(float x) {
#if __has_builtin(__builtin_amdgcn_exp2f)
    return __builtin_amdgcn_exp2f(x);
#else
    float r; asm("v_exp_f32 %0, %1" : "=v"(r) : "v"(x)); return r;
#endif
}
__device__ __forceinline__ void gload_lds16(const void* g, void* l) {
    __builtin_amdgcn_global_load_lds(
        (const __attribute__((address_space(1))) unsigned int*)g,
        (__attribute__((address_space(3))) unsigned int*)l, 16, 0, 0);
}

// ---------------------------------------------------------------------------
// prep_misc: fused {pack_adj | cvt_h | cvt_wT}. 8192 + 1024 + 32 blocks.
// ---------------------------------------------------------------------------
__global__ __launch_bounds__(256) void prep_misc(const float* __restrict__ h,
                                                 const int* __restrict__ adj,
                                                 const float* __restrict__ W,
                                                 u16* __restrict__ hb,
                                                 u16* __restrict__ WbT,
                                                 u32* __restrict__ bits) {
    const int bid = blockIdx.x;
    const int t = threadIdx.x;
    if (bid < 8192) {
        const int lane = t & 63;
        const size_t e0 = ((size_t)bid * 256 + t) * 4;
        const int4 v = *reinterpret_cast<const int4*>(adj + e0);
        u32 x = (v.x ? 1u : 0u) | (v.y ? 2u : 0u) | (v.z ? 4u : 0u) | (v.w ? 8u : 0u);
        {   const u32 r = (u32)__shfl_xor((int)x, 1);
            const int sh = (lane & 1) * 4;  x = (x << sh) | (r << (4 - sh)); }
        {   const u32 r = (u32)__shfl_xor((int)x, 2);
            const int sh = (lane & 2) * 4;  x = (x << sh) | (r << (8 - sh)); }
        {   const u32 r = (u32)__shfl_xor((int)x, 4);
            const int sh = (lane & 4) * 4;  x = (x << sh) | (r << (16 - sh)); }
        if ((lane & 7) == 0) bits[e0 >> 5] = x;
    } else if (bid < 9216) {
        const int i = ((bid - 8192) * 256 + t) * 8;
        const float4 v0 = *reinterpret_cast<const float4*>(h + i);
        const float4 v1 = *reinterpret_cast<const float4*>(h + i + 4);
        u16x8v o;
        o[0]=f2b(v0.x); o[1]=f2b(v0.y); o[2]=f2b(v0.z); o[3]=f2b(v0.w);
        o[4]=f2b(v1.x); o[5]=f2b(v1.y); o[6]=f2b(v1.z); o[7]=f2b(v1.w);
        *reinterpret_cast<u16x8v*>(hb + i) = o;
    } else {
        __shared__ float T[64][65];
        const int bb = bid - 9216;
        const int hh = bb & 7;
        const int n0 = hh * 64, k0 = (bb >> 3) * 64;
        const int r4 = t >> 6, c = t & 63;
        #pragma unroll
        for (int p = 0; p < 16; ++p) {
            const int r = p * 4 + r4;
            T[r][c] = W[(size_t)(k0 + r) * NH + n0 + c];
        }
        __syncthreads();
        #pragma unroll
        for (int p = 0; p < 16; ++p) {
            const int r = p * 4 + r4;
            WbT[(size_t)(n0 + r) * FIN + k0 + c] = f2b(T[c][r]);
        }
    }
}

// ---------------------------------------------------------------------------
// gemm_whT: Wh = hb @ WbT^T, 64x64 tile, grid 1024, XCD-chunked.
// Epilogue: exact-f32 e_src/e_dst from accumulators + transposed bf16 WhT.
// (r11 version, known-good)
// ---------------------------------------------------------------------------
__global__ __launch_bounds__(256) void gemm_whT(const u16* __restrict__ hb,
                                                const u16* __restrict__ WbT,
                                                const float* __restrict__ avec,
                                                u16* __restrict__ WhT,
                                                float* __restrict__ esrc,
                                                float* __restrict__ edst) {
    __shared__ u16 Al[2][64 * 64];
    __shared__ u16 Bl[2][64 * 64];
    const int t = threadIdx.x, wv = t >> 6, lane = t & 63;
    const int g = lane >> 4, l15 = lane & 15;
    const int lid = (blockIdx.x & 7) * 128 + (blockIdx.x >> 3);
    const int m0 = (lid >> 3) * 64;
    const int h  = lid & 7;
    const int lr = lane >> 3;
    const int sch = (lane & 7) ^ lr;
    const int bh = (m0 >> 10) * HEADS + h;

    f32x4 acc[4] = {};

    auto stageA = [&](int buf, int k0) {
        #pragma unroll
        for (int c = 0; c < 2; ++c) {
            const int rowb = wv * 16 + c * 8;
            gload_lds16(hb + (size_t)(m0 + rowb + lr) * FIN + k0 + sch * 8,
                        &Al[buf][rowb * 64]);
        }
    };
    auto stageB = [&](int buf, int k0) {
        #pragma unroll
        for (int c = 0; c < 2; ++c) {
            const int rowb = wv * 16 + c * 8;
            gload_lds16(WbT + (size_t)(h * 64 + rowb + lr) * FIN + k0 + sch * 8,
                        &Bl[buf][rowb * 64]);
        }
    };

    stageA(0, 0); stageB(0, 0);
    __syncthreads();
    for (int kt = 0; kt < 4; ++kt) {
        const int buf = kt & 1;
        if (kt < 3) { stageA(buf ^ 1, (kt + 1) * 64); stageB(buf ^ 1, (kt + 1) * 64); }
        #pragma unroll
        for (int ks = 0; ks < 2; ++ks) {
            const int ch = (ks * 4 + g) ^ (l15 & 7);
            const bf16x8 afr = *reinterpret_cast<const bf16x8*>(
                &Al[buf][(wv * 16 + l15) * 64 + ch * 8]);
            #pragma unroll
            for (int n = 0; n < 4; ++n) {
                const bf16x8 bfr = *reinterpret_cast<const bf16x8*>(
                    &Bl[buf][(n * 16 + l15) * 64 + ch * 8]);
                acc[n] = __builtin_amdgcn_mfma_f32_16x16x32_bf16(afr, bfr, acc[n], 0, 0, 0);
            }
        }
        __syncthreads();
    }

    // ---- e epilogue (exact f32, exp2 domain) ----
    {
        float as_[4], ad_[4];
        #pragma unroll
        for (int n = 0; n < 4; ++n) {
            as_[n] = avec[h * 128 + n * 16 + l15] * LOG2E;
            ad_[n] = avec[h * 128 + 64 + n * 16 + l15] * LOG2E;
        }
        #pragma unroll
        for (int r = 0; r < 4; ++r) {
            float ps = acc[0][r] * as_[0] + acc[1][r] * as_[1]
                     + acc[2][r] * as_[2] + acc[3][r] * as_[3];
            float pd = acc[0][r] * ad_[0] + acc[1][r] * ad_[1]
                     + acc[2][r] * ad_[2] + acc[3][r] * ad_[3];
            #pragma unroll
            for (int off = 1; off < 16; off <<= 1) {
                ps += __shfl_xor(ps, off);
                pd += __shfl_xor(pd, off);
            }
            if (l15 == 0) {
                const int i = (m0 + wv * 16 + g * 4 + r) & (NN - 1);
                esrc[(size_t)bh * NN + i] = ps;
                edst[(size_t)bh * NN + i] = pd;
            }
        }
    }

    // ---- WhT store via LDS bounce (coalesced) ----
    u16* scr = &Al[0][0];
    #pragma unroll
    for (int n = 0; n < 4; ++n) {
        u16x4v pk;
        #pragma unroll
        for (int r = 0; r < 4; ++r) pk[r] = f2b(acc[n][r]);
        *reinterpret_cast<u16x4v*>(&scr[(n * 16 + l15) * 72 + wv * 16 + g * 4]) = pk;
    }
    __syncthreads();
    const int il0 = m0 & (NN - 1);
    const int f = t >> 2, q = t & 3;
    const u16x8v v0 = *reinterpret_cast<const u16x8v*>(&scr[f * 72 + q * 16]);
    const u16x8v v1 = *reinterpret_cast<const u16x8v*>(&scr[f * 72 + q * 16 + 8]);
    u16* dst = &WhT[((size_t)bh * 64 + f) * NN + il0 + q * 16];
    *reinterpret_cast<u16x8v*>(dst)     = v0;
    *reinterpret_cast<u16x8v*>(dst + 8) = v1;
}

// ---------------------------------------------------------------------------
// attn_pv v10: dual-A + many-block. 128 thr / 2 waves / 64-row block
// (wave owns 32 rows as two 16-row A-frags sharing each B ds_read), grid
// 1024 -> 4 independent blocks/CU. 16KB V dbuf, counted vmcnt(8)+s_barrier,
// 2-deep ed/bits register prefetch, setprio, dsum via mfma(P, ones).
// ---------------------------------------------------------------------------
__global__ __launch_bounds__(128, 2) void attn_pv(const u32* __restrict__ bits,
                                                  const u16* __restrict__ WhT,
                                                  const float* __restrict__ esrc,
                                                  const float* __restrict__ edst,
                                                  float* __restrict__ out) {
    __shared__ u16 Bs[2][64 * 64];             // 16 KB, V tile dbuf
    const int t = threadIdx.x, wv = t >> 6, lane = t & 63;
    const int g = lane >> 4, l15 = lane & 15;
    const int lr = lane >> 3, sch = (lane & 7) ^ lr;

    // XCD chunk: 128 consecutive lids (one batch) per XCD
    const int lid = (blockIdx.x & 7) * 128 + (blockIdx.x >> 3);
    const int it = lid & 15, h = (lid >> 4) & 7, b = lid >> 7;
    const int i0 = it * 64;
    const int bh = b * HEADS + h;
    const int row0 = i0 + wv * 32 + l15;       // mf=0 row; mf=1 at +16

    const float es0 = esrc[(size_t)bh * NN + row0];
    const float es1 = esrc[(size_t)bh * NN + row0 + 16];
    const u16*  whb = WhT + (size_t)bh * 64 * NN;
    const float* ed = edst + (size_t)bh * NN + 8 * g;
    const u32*  bitrow0 = bits + (size_t)(b * NN + row0) * 32;
    const u32*  bitrow1 = bitrow0 + 16 * 32;

    auto stage = [&](int buf, int j0) {
        #pragma unroll
        for (int c = 0; c < 4; ++c) {
            const int fb = wv * 32 + c * 8;
            gload_lds16(whb + (size_t)(fb + lr) * NN + j0 + sch * 8,
                        &Bs[buf][fb * 64]);
        }
    };

    stage(0, 0);
    // 2-deep register prefetch slots (slot = parity of step s)
    float4 peA[2], peB[2];
    u32    pw0[2], pw1[2];
    #pragma unroll
    for (int s = 0; s < 2; ++s) {
        peA[s] = *(const float4*)(ed + s * 32);
        peB[s] = *(const float4*)(ed + s * 32 + 4);
        pw0[s] = bitrow0[s];
        pw1[s] = bitrow1[s];
    }
    __syncthreads();

    f32x4 acc0[4] = {}, acc1[4] = {};
    f32x4 dsum0 = {}, dsum1 = {};
    bf16x8 ones;
    #pragma unroll
    for (int q = 0; q < 8; ++q) ones[q] = (short)0x3F80;   // bf16(1.0)

    for (int tt = 0; tt < 16; ++tt) {
        const int buf = tt & 1;
        const bool more = (tt < 15);
        if (more) {
            stage(buf ^ 1, (tt + 1) * 64);
            asm volatile("" ::: "memory");     // pin: prefetches stay after stage
        }
        #pragma unroll
        for (int ks = 0; ks < 2; ++ks) {
            const int s = tt * 2 + ks;
            const float4 e0 = peA[ks], e1 = peB[ks];
            const u32 w0 = pw0[ks], w1 = pw1[ks];
            if (more) {                        // refill slot with step s+2
                peA[ks] = *(const float4*)(ed + (s + 2) * 32);
                peB[ks] = *(const float4*)(ed + (s + 2) * 32 + 4);
                pw0[ks] = bitrow0[s + 2];
                pw1[ks] = bitrow1[s + 2];
            }
            // B fragments early: ds latency hides under p-gen
            const int chb = ((ks * 4 + g) ^ (l15 & 7)) * 8;
            const bf16x8 v0 = *(const bf16x8*)(&Bs[buf][(0 * 16 + l15) * 64 + chb]);
            const bf16x8 v1 = *(const bf16x8*)(&Bs[buf][(1 * 16 + l15) * 64 + chb]);
            const bf16x8 v2 = *(const bf16x8*)(&Bs[buf][(2 * 16 + l15) * 64 + chb]);
            const bf16x8 v3 = *(const bf16x8*)(&Bs[buf][(3 * 16 + l15) * 64 + chb]);

            float ej[8];
            ej[0]=e0.x; ej[1]=e0.y; ej[2]=e0.z; ej[3]=e0.w;
            ej[4]=e1.x; ej[5]=e1.y; ej[6]=e1.z; ej[7]=e1.w;
            const u32 by0 = (w0 >> (8 * g)) & 0xffu;
            const u32 by1 = (w1 >> (8 * g)) & 0xffu;
            float p0[8], p1[8];
            #pragma unroll
            for (int q = 0; q < 8; ++q) {
                float s0 = es0 + ej[q];
                float s1 = es1 + ej[q];
                s0 = fmaxf(s0, ALPHA * s0);
                s1 = fmaxf(s1, ALPHA * s1);
                s0 = ((by0 >> q) & 1u) ? s0 : -1e30f;
                s1 = ((by1 >> q) & 1u) ? s1 : -1e30f;
                p0[q] = fexp2(s0);
                p1[q] = fexp2(s1);
            }
            union { u32 u[4]; bf16x8 v; } af0, af1;
            #pragma unroll
            for (int qp = 0; qp < 4; ++qp) {
                union { __hip_bfloat162 b2; u32 w; } c0, c1;
                c0.b2 = __float22bfloat162_rn(make_float2(p0[2*qp], p0[2*qp+1]));
                c1.b2 = __float22bfloat162_rn(make_float2(p1[2*qp], p1[2*qp+1]));
                af0.u[qp] = c0.w;
                af1.u[qp] = c1.w;
            }
            __builtin_amdgcn_s_setprio(1);
            acc0[0] = __builtin_amdgcn_mfma_f32_16x16x32_bf16(af0.v, v0, acc0[0], 0, 0, 0);
            acc1[0] = __builtin_amdgcn_mfma_f32_16x16x32_bf16(af1.v, v0, acc1[0], 0, 0, 0);
            acc0[1] = __builtin_amdgcn_mfma_f32_16x16x32_bf16(af0.v, v1, acc0[1], 0, 0, 0);
            acc1[1] = __builtin_amdgcn_mfma_f32_16x16x32_bf16(af1.v, v1, acc1[1], 0, 0, 0);
            acc0[2] = __builtin_amdgcn_mfma_f32_16x16x32_bf16(af0.v, v2, acc0[2], 0, 0, 0);
            acc1[2] = __builtin_amdgcn_mfma_f32_16x16x32_bf16(af1.v, v2, acc1[2], 0, 0, 0);
            acc0[3] = __builtin_amdgcn_mfma_f32_16x16x32_bf16(af0.v, v3, acc0[3], 0, 0, 0);
            acc1[3] = __builtin_amdgcn_mfma_f32_16x16x32_bf16(af1.v, v3, acc1[3], 0, 0, 0);
            dsum0   = __builtin_amdgcn_mfma_f32_16x16x32_bf16(af0.v, ones, dsum0, 0, 0, 0);
            dsum1   = __builtin_amdgcn_mfma_f32_16x16x32_bf16(af1.v, ones, dsum1, 0, 0, 0);
            __builtin_amdgcn_s_setprio(0);
        }
        if (more) {
            // per-wave VMEM newer than the last stage load: 8 prefetches
            // -> vmcnt(8) guarantees stage landed, prefetches stay in flight.
            asm volatile("s_waitcnt vmcnt(8)" ::: "memory");
            __builtin_amdgcn_s_barrier();
        }
    }

    float inv0[4], inv1[4];
    #pragma unroll
    for (int r = 0; r < 4; ++r) { inv0[r] = 1.0f / dsum0[r]; inv1[r] = 1.0f / dsum1[r]; }
    #pragma unroll
    for (int n = 0; n < 4; ++n)
        #pragma unroll
        for (int r = 0; r < 4; ++r) {
            const int io0 = i0 + wv * 32 + g * 4 + r;
            out[(size_t)(b * NN + io0) * NH + h * 64 + n * 16 + l15] =
                acc0[n][r] * inv0[r];
            out[(size_t)(b * NN + io0 + 16) * NH + h * 64 + n * 16 + l15] =
                acc1[n][r] * inv1[r];
        }
}

// ---------------------------------------------------------------------------
extern "C" void kernel_launch(void* const* d_in, const int* in_sizes, int n_in,
                              void* d_out, int out_size, void* d_ws, size_t ws_size,
                              hipStream_t stream) {
    const float* h   = (const float*)d_in[0];
    const int*   adj = (const int*)  d_in[1];
    const float* W   = (const float*)d_in[2];
    const float* a   = (const float*)d_in[3];
    float* out = (float*)d_out;

    char* p = (char*)d_ws;
    u16*   hb   = (u16*)p;   p += (size_t)BS * NN * FIN * 2;        // 4 MB
    u16*   WbT  = (u16*)p;   p += (size_t)NH * FIN * 2;             // 256 KB
    u16*   WhT  = (u16*)p;   p += (size_t)BS * HEADS * FO * NN * 2; // 8 MB
    float* esrc = (float*)p; p += (size_t)BS * HEADS * NN * 4;      // 256 KB
    float* edst = (float*)p; p += (size_t)BS * HEADS * NN * 4;      // 256 KB
    u32*   bits = (u32*)p;                                          // 1 MB

    prep_misc<<<9248, 256, 0, stream>>>(h, adj, W, hb, WbT, bits);
    gemm_whT <<<1024, 256, 0, stream>>>(hb, WbT, a, WhT, esrc, edst);
    attn_pv  <<<1024, 128, 0, stream>>>(bits, WhT, esrc, edst, out);
}

// Round 15
// 53.386 us; speedup vs baseline: 2.0744x; 1.0609x over previous
//
#include <hip/hip_runtime.h>
#include <hip/hip_bf16.h>
#include <math.h>

#define BS 8
#define NN 1024
#define FIN 256
#define HEADS 8
#define FO 64
#define NH (HEADS*FO)   /* 512 */
static constexpr float ALPHA = 0.2f;
static constexpr float LOG2E = 1.4426950408889634f;

typedef short bf16x8 __attribute__((ext_vector_type(8)));
typedef float f32x4  __attribute__((ext_vector_type(4)));
typedef unsigned short u16;
typedef unsigned u32;
typedef u16 u16x4v __attribute__((ext_vector_type(4)));
typedef u16 u16x8v __attribute__((ext_vector_type(8)));

__device__ __forceinline__ u16 f2b(float x) {
    __hip_bfloat16 b = __float2bfloat16(x);
    return *reinterpret_cast<u16*>(&b);
}
__device__ __forceinline__ float fexp2(float x) {
#if __has_builtin(__builtin_amdgcn_exp2f)
    return __builtin_amdgcn_exp2f(x);
#else
    float r; asm("v_exp_f32 %0, %1" : "=v"(r) : "v"(x)); return r;
#endif
}
__device__ __forceinline__ void gload_lds16(const void* g, void* l) {
    __builtin_amdgcn_global_load_lds(
        (const __attribute__((address_space(1))) unsigned int*)g,
        (__attribute__((address_space(3))) unsigned int*)l, 16, 0, 0);
}

// ---------------------------------------------------------------------------
// prep_misc: fused {pack_adj | cvt_h | cvt_wT}. 8192 + 1024 + 32 blocks.
// ---------------------------------------------------------------------------
__global__ __launch_bounds__(256) void prep_misc(const float* __restrict__ h,
                                                 const int* __restrict__ adj,
                                                 const float* __restrict__ W,
                                                 u16* __restrict__ hb,
                                                 u16* __restrict__ WbT,
                                                 u32* __restrict__ bits) {
    const int bid = blockIdx.x;
    const int t = threadIdx.x;
    if (bid < 8192) {
        const int lane = t & 63;
        const size_t e0 = ((size_t)bid * 256 + t) * 4;
        const int4 v = *reinterpret_cast<const int4*>(adj + e0);
        u32 x = (v.x ? 1u : 0u) | (v.y ? 2u : 0u) | (v.z ? 4u : 0u) | (v.w ? 8u : 0u);
        {   const u32 r = (u32)__shfl_xor((int)x, 1);
            const int sh = (lane & 1) * 4;  x = (x << sh) | (r << (4 - sh)); }
        {   const u32 r = (u32)__shfl_xor((int)x, 2);
            const int sh = (lane & 2) * 4;  x = (x << sh) | (r << (8 - sh)); }
        {   const u32 r = (u32)__shfl_xor((int)x, 4);
            const int sh = (lane & 4) * 4;  x = (x << sh) | (r << (16 - sh)); }
        if ((lane & 7) == 0) bits[e0 >> 5] = x;
    } else if (bid < 9216) {
        const int i = ((bid - 8192) * 256 + t) * 8;
        const float4 v0 = *reinterpret_cast<const float4*>(h + i);
        const float4 v1 = *reinterpret_cast<const float4*>(h + i + 4);
        u16x8v o;
        o[0]=f2b(v0.x); o[1]=f2b(v0.y); o[2]=f2b(v0.z); o[3]=f2b(v0.w);
        o[4]=f2b(v1.x); o[5]=f2b(v1.y); o[6]=f2b(v1.z); o[7]=f2b(v1.w);
        *reinterpret_cast<u16x8v*>(hb + i) = o;
    } else {
        __shared__ float T[64][65];
        const int bb = bid - 9216;
        const int hh = bb & 7;
        const int n0 = hh * 64, k0 = (bb >> 3) * 64;
        const int r4 = t >> 6, c = t & 63;
        #pragma unroll
        for (int p = 0; p < 16; ++p) {
            const int r = p * 4 + r4;
            T[r][c] = W[(size_t)(k0 + r) * NH + n0 + c];
        }
        __syncthreads();
        #pragma unroll
        for (int p = 0; p < 16; ++p) {
            const int r = p * 4 + r4;
            WbT[(size_t)(n0 + r) * FIN + k0 + c] = f2b(T[c][r]);
        }
    }
}

// ---------------------------------------------------------------------------
// gemm_whT: Wh = hb @ WbT^T, 64x64 tile, grid 1024, XCD-chunked.
// Epilogue: exact-f32 e_src/e_dst from accumulators + transposed bf16 WhT.
// ---------------------------------------------------------------------------
__global__ __launch_bounds__(256) void gemm_whT(const u16* __restrict__ hb,
                                                const u16* __restrict__ WbT,
                                                const float* __restrict__ avec,
                                                u16* __restrict__ WhT,
                                                float* __restrict__ esrc,
                                                float* __restrict__ edst) {
    __shared__ u16 Al[2][64 * 64];
    __shared__ u16 Bl[2][64 * 64];
    const int t = threadIdx.x, wv = t >> 6, lane = t & 63;
    const int g = lane >> 4, l15 = lane & 15;
    const int lid = (blockIdx.x & 7) * 128 + (blockIdx.x >> 3);
    const int m0 = (lid >> 3) * 64;
    const int h  = lid & 7;
    const int lr = lane >> 3;
    const int sch = (lane & 7) ^ lr;
    const int bh = (m0 >> 10) * HEADS + h;

    f32x4 acc[4] = {};

    auto stageA = [&](int buf, int k0) {
        #pragma unroll
        for (int c = 0; c < 2; ++c) {
            const int rowb = wv * 16 + c * 8;
            gload_lds16(hb + (size_t)(m0 + rowb + lr) * FIN + k0 + sch * 8,
                        &Al[buf][rowb * 64]);
        }
    };
    auto stageB = [&](int buf, int k0) {
        #pragma unroll
        for (int c = 0; c < 2; ++c) {
            const int rowb = wv * 16 + c * 8;
            gload_lds16(WbT + (size_t)(h * 64 + rowb + lr) * FIN + k0 + sch * 8,
                        &Bl[buf][rowb * 64]);
        }
    };

    stageA(0, 0); stageB(0, 0);
    __syncthreads();
    for (int kt = 0; kt < 4; ++kt) {
        const int buf = kt & 1;
        if (kt < 3) { stageA(buf ^ 1, (kt + 1) * 64); stageB(buf ^ 1, (kt + 1) * 64); }
        #pragma unroll
        for (int ks = 0; ks < 2; ++ks) {
            const int ch = (ks * 4 + g) ^ (l15 & 7);
            const bf16x8 afr = *reinterpret_cast<const bf16x8*>(
                &Al[buf][(wv * 16 + l15) * 64 + ch * 8]);
            #pragma unroll
            for (int n = 0; n < 4; ++n) {
                const bf16x8 bfr = *reinterpret_cast<const bf16x8*>(
                    &Bl[buf][(n * 16 + l15) * 64 + ch * 8]);
                acc[n] = __builtin_amdgcn_mfma_f32_16x16x32_bf16(afr, bfr, acc[n], 0, 0, 0);
            }
        }
        __syncthreads();
    }

    // ---- e epilogue (exact f32, exp2 domain) ----
    {
        float as_[4], ad_[4];
        #pragma unroll
        for (int n = 0; n < 4; ++n) {
            as_[n] = avec[h * 128 + n * 16 + l15] * LOG2E;
            ad_[n] = avec[h * 128 + 64 + n * 16 + l15] * LOG2E;
        }
        #pragma unroll
        for (int r = 0; r < 4; ++r) {
            float ps = acc[0][r] * as_[0] + acc[1][r] * as_[1]
                     + acc[2][r] * as_[2] + acc[3][r] * as_[3];
            float pd = acc[0][r] * ad_[0] + acc[1][r] * ad_[1]
                     + acc[2][r] * ad_[2] + acc[3][r] * ad_[3];
            #pragma unroll
            for (int off = 1; off < 16; off <<= 1) {
                ps += __shfl_xor(ps, off);
                pd += __shfl_xor(pd, off);
            }
            if (l15 == 0) {
                const int i = (m0 + wv * 16 + g * 4 + r) & (NN - 1);
                esrc[(size_t)bh * NN + i] = ps;
                edst[(size_t)bh * NN + i] = pd;
            }
        }
    }

    // ---- WhT store via LDS bounce (coalesced) ----
    u16* scr = &Al[0][0];
    #pragma unroll
    for (int n = 0; n < 4; ++n) {
        u16x4v pk;
        #pragma unroll
        for (int r = 0; r < 4; ++r) pk[r] = f2b(acc[n][r]);
        *reinterpret_cast<u16x4v*>(&scr[(n * 16 + l15) * 72 + wv * 16 + g * 4]) = pk;
    }
    __syncthreads();
    const int il0 = m0 & (NN - 1);
    const int f = t >> 2, q = t & 3;
    const u16x8v v0 = *reinterpret_cast<const u16x8v*>(&scr[f * 72 + q * 16]);
    const u16x8v v1 = *reinterpret_cast<const u16x8v*>(&scr[f * 72 + q * 16 + 8]);
    u16* dst = &WhT[((size_t)bh * 64 + f) * NN + il0 + q * 16];
    *reinterpret_cast<u16x8v*>(dst)     = v0;
    *reinterpret_cast<u16x8v*>(dst + 8) = v1;
}

// ---------------------------------------------------------------------------
// attn_pv v11: r11 base (256 thr / 4 waves / 128 rows, dual-A, grid 512,
// XCD-chunked) + 3-buffer 2-tiles-ahead V staging. Block count is
// grid-capped at 2/CU, so the 3rd 8KB buffer is free; stage slack grows to
// ~2 tile bodies. Exact counted vmcnt(18) at tile boundary. dsum via MFMA.
// ---------------------------------------------------------------------------
__global__ __launch_bounds__(256, 2) void attn_pv(const u32* __restrict__ bits,
                                                  const u16* __restrict__ WhT,
                                                  const float* __restrict__ esrc,
                                                  const float* __restrict__ edst,
                                                  float* __restrict__ out) {
    __shared__ u16 Bs[3][64 * 64];             // 24 KB: 3-deep V tile ring
    const int t = threadIdx.x, wv = t >> 6, lane = t & 63;
    const int g = lane >> 4, l15 = lane & 15;
    const int lr = lane >> 3, sch = (lane & 7) ^ lr;

    // XCD chunk: 64 consecutive lids (8 i-chunks x 8 heads of one batch)/XCD
    const int lid = (blockIdx.x & 7) * 64 + (blockIdx.x >> 3);
    const int it = lid & 7, h = (lid >> 3) & 7, b = lid >> 6;
    const int i0 = it * 128;
    const int bh = b * HEADS + h;
    const int row0 = i0 + wv * 32 + l15;       // mf=0 row; mf=1 at +16

    const float es0 = esrc[(size_t)bh * NN + row0];
    const float es1 = esrc[(size_t)bh * NN + row0 + 16];
    const u16*  whb = WhT + (size_t)bh * 64 * NN;
    const float* ed = edst + (size_t)bh * NN + 8 * g;
    const u32*  bitrow0 = bits + (size_t)(b * NN + row0) * 32;
    const u32*  bitrow1 = bitrow0 + 16 * 32;

    auto stage = [&](int buf, int j0) {
        #pragma unroll
        for (int c = 0; c < 2; ++c) {
            const int fb = wv * 16 + c * 8;
            gload_lds16(whb + (size_t)(fb + lr) * NN + j0 + sch * 8,
                        &Bs[buf][fb * 64]);
        }
    };

    // ---- prologue: stage tiles 0,1; prefetch steps 0,1 ----
    stage(0, 0);
    stage(1, 64);
    float4 peA[2], peB[2];
    u32    pw0[2], pw1[2];
    #pragma unroll
    for (int s = 0; s < 2; ++s) {
        peA[s] = *(const float4*)(ed + s * 32);
        peB[s] = *(const float4*)(ed + s * 32 + 4);
        pw0[s] = bitrow0[s];
        pw1[s] = bitrow1[s];
    }
    // tile 0 ready: newer = stage(1) 2 + prefetch 8 = 10
    asm volatile("s_waitcnt vmcnt(10)" ::: "memory");
    __builtin_amdgcn_s_barrier();

    f32x4 acc0[4] = {}, acc1[4] = {};
    f32x4 dsum0 = {}, dsum1 = {};
    bf16x8 ones;
    #pragma unroll
    for (int q = 0; q < 8; ++q) ones[q] = (short)0x3F80;   // bf16(1.0)

    int bufR = 0, bufW = 2;
    for (int tt = 0; tt < 16; ++tt) {
        const bool more = (tt < 15);
        // stage tile tt+2 (clamped; duplicate stages land in unread buffers)
        const int jn = (tt < 14) ? (tt + 2) * 64 : 15 * 64;
        stage(bufW, jn);
        asm volatile("" ::: "memory");         // pin: prefetches stay after stage
        const int bsBase = bufR * 8192;        // bytes
        #pragma unroll
        for (int ks = 0; ks < 2; ++ks) {
            const int s = tt * 2 + ks;
            const float4 e0 = peA[ks], e1 = peB[ks];
            const u32 w0 = pw0[ks], w1 = pw1[ks];
            if (more) {                        // refill slot with step s+2
                peA[ks] = *(const float4*)(ed + (s + 2) * 32);
                peB[ks] = *(const float4*)(ed + (s + 2) * 32 + 4);
                pw0[ks] = bitrow0[s + 2];
                pw1[ks] = bitrow1[s + 2];
            }
            // B fragments early: ds latency hides under p-gen
            const char* bsb = (const char*)Bs + bsBase
                            + l15 * 128 + (((ks * 4 + g) ^ (l15 & 7)) << 4);
            const bf16x8 v0 = *(const bf16x8*)(bsb);
            const bf16x8 v1 = *(const bf16x8*)(bsb + 2048);
            const bf16x8 v2 = *(const bf16x8*)(bsb + 4096);
            const bf16x8 v3 = *(const bf16x8*)(bsb + 6144);

            float ej[8];
            ej[0]=e0.x; ej[1]=e0.y; ej[2]=e0.z; ej[3]=e0.w;
            ej[4]=e1.x; ej[5]=e1.y; ej[6]=e1.z; ej[7]=e1.w;
            const u32 by0 = (w0 >> (8 * g)) & 0xffu;
            const u32 by1 = (w1 >> (8 * g)) & 0xffu;
            float p0[8], p1[8];
            #pragma unroll
            for (int q = 0; q < 8; ++q) {
                float s0 = es0 + ej[q];
                float s1 = es1 + ej[q];
                s0 = fmaxf(s0, ALPHA * s0);
                s1 = fmaxf(s1, ALPHA * s1);
                s0 = ((by0 >> q) & 1u) ? s0 : -1e30f;
                s1 = ((by1 >> q) & 1u) ? s1 : -1e30f;
                p0[q] = fexp2(s0);
                p1[q] = fexp2(s1);
            }
            union { u32 u[4]; bf16x8 v; } af0, af1;
            #pragma unroll
            for (int qp = 0; qp < 4; ++qp) {
                union { __hip_bfloat162 b2; u32 w; } c0, c1;
                c0.b2 = __float22bfloat162_rn(make_float2(p0[2*qp], p0[2*qp+1]));
                c1.b2 = __float22bfloat162_rn(make_float2(p1[2*qp], p1[2*qp+1]));
                af0.u[qp] = c0.w;
                af1.u[qp] = c1.w;
            }
            __builtin_amdgcn_s_setprio(1);
            acc0[0] = __builtin_amdgcn_mfma_f32_16x16x32_bf16(af0.v, v0, acc0[0], 0, 0, 0);
            acc1[0] = __builtin_amdgcn_mfma_f32_16x16x32_bf16(af1.v, v0, acc1[0], 0, 0, 0);
            acc0[1] = __builtin_amdgcn_mfma_f32_16x16x32_bf16(af0.v, v1, acc0[1], 0, 0, 0);
            acc1[1] = __builtin_amdgcn_mfma_f32_16x16x32_bf16(af1.v, v1, acc1[1], 0, 0, 0);
            acc0[2] = __builtin_amdgcn_mfma_f32_16x16x32_bf16(af0.v, v2, acc0[2], 0, 0, 0);
            acc1[2] = __builtin_amdgcn_mfma_f32_16x16x32_bf16(af1.v, v2, acc1[2], 0, 0, 0);
            acc0[3] = __builtin_amdgcn_mfma_f32_16x16x32_bf16(af0.v, v3, acc0[3], 0, 0, 0);
            acc1[3] = __builtin_amdgcn_mfma_f32_16x16x32_bf16(af1.v, v3, acc1[3], 0, 0, 0);
            dsum0   = __builtin_amdgcn_mfma_f32_16x16x32_bf16(af0.v, ones, dsum0, 0, 0, 0);
            dsum1   = __builtin_amdgcn_mfma_f32_16x16x32_bf16(af1.v, ones, dsum1, 0, 0, 0);
            __builtin_amdgcn_s_setprio(0);
        }
        if (more) {
            // need stage(tt+1), issued in iter tt-1. Newer VMEM since then:
            // pf(tt-1) 8 + stage(tt+2) 2 + pf(tt) 8 = 18 -> vmcnt(18)
            asm volatile("s_waitcnt vmcnt(18)" ::: "memory");
            __builtin_amdgcn_s_barrier();
        }
        bufR = (bufR == 2) ? 0 : bufR + 1;
        bufW = (bufW == 2) ? 0 : bufW + 1;
    }

    float inv0[4], inv1[4];
    #pragma unroll
    for (int r = 0; r < 4; ++r) { inv0[r] = 1.0f / dsum0[r]; inv1[r] = 1.0f / dsum1[r]; }
    #pragma unroll
    for (int n = 0; n < 4; ++n)
        #pragma unroll
        for (int r = 0; r < 4; ++r) {
            const int io0 = i0 + wv * 32 + g * 4 + r;
            out[(size_t)(b * NN + io0) * NH + h * 64 + n * 16 + l15] =
                acc0[n][r] * inv0[r];
            out[(size_t)(b * NN + io0 + 16) * NH + h * 64 + n * 16 + l15] =
                acc1[n][r] * inv1[r];
        }
}

// ---------------------------------------------------------------------------
extern "C" void kernel_launch(void* const* d_in, const int* in_sizes, int n_in,
                              void* d_out, int out_size, void* d_ws, size_t ws_size,
                              hipStream_t stream) {
    const float* h   = (const float*)d_in[0];
    const int*   adj = (const int*)  d_in[1];
    const float* W   = (const float*)d_in[2];
    const float* a   = (const float*)d_in[3];
    float* out = (float*)d_out;

    char* p = (char*)d_ws;
    u16*   hb   = (u16*)p;   p += (size_t)BS * NN * FIN * 2;        // 4 MB
    u16*   WbT  = (u16*)p;   p += (size_t)NH * FIN * 2;             // 256 KB
    u16*   WhT  = (u16*)p;   p += (size_t)BS * HEADS * FO * NN * 2; // 8 MB
    float* esrc = (float*)p; p += (size_t)BS * HEADS * NN * 4;      // 256 KB
    float* edst = (float*)p; p += (size_t)BS * HEADS * NN * 4;      // 256 KB
    u32*   bits = (u32*)p;                                          // 1 MB

    prep_misc<<<9248, 256, 0, stream>>>(h, adj, W, hb, WbT, bits);
    gemm_whT <<<1024, 256, 0, stream>>>(hb, WbT, a, WhT, esrc, edst);
    attn_pv  <<<512, 256, 0, stream>>>(bits, WhT, esrc, edst, out);
}

// Round 16
// 50.284 us; speedup vs baseline: 2.2023x; 1.0617x over previous
//
#include <hip/hip_runtime.h>
#include <hip/hip_bf16.h>
#include <math.h>

#define BS 8
#define NN 1024
#define FIN 256
#define HEADS 8
#define FO 64
#define NH (HEADS*FO)   /* 512 */
static constexpr float ALPHA = 0.2f;
static constexpr float LOG2E = 1.4426950408889634f;

typedef short bf16x8 __attribute__((ext_vector_type(8)));
typedef float f32x4  __attribute__((ext_vector_type(4)));
typedef float f32x2  __attribute__((ext_vector_type(2)));
typedef unsigned short u16;
typedef unsigned u32;
typedef u16 u16x4v __attribute__((ext_vector_type(4)));
typedef u16 u16x8v __attribute__((ext_vector_type(8)));

__device__ __forceinline__ u16 f2b(float x) {
    __hip_bfloat16 b = __float2bfloat16(x);
    return *reinterpret_cast<u16*>(&b);
}
__device__ __forceinline__ float fexp2(float x) {
#if __has_builtin(__builtin_amdgcn_exp2f)
    return __builtin_amdgcn_exp2f(x);
#else
    float r; asm("v_exp_f32 %0, %1" : "=v"(r) : "v"(x)); return r;
#endif
}
__device__ __forceinline__ void gload_lds16(const void* g, void* l) {
    __builtin_amdgcn_global_load_lds(
        (const __attribute__((address_space(1))) unsigned int*)g,
        (__attribute__((address_space(3))) unsigned int*)l, 16, 0, 0);
}

// ---------------------------------------------------------------------------
// prep_misc: fused {pack_adj | cvt_h | cvt_wT}. 8192 + 1024 + 32 blocks.
// ---------------------------------------------------------------------------
__global__ __launch_bounds__(256) void prep_misc(const float* __restrict__ h,
                                                 const int* __restrict__ adj,
                                                 const float* __restrict__ W,
                                                 u16* __restrict__ hb,
                                                 u16* __restrict__ WbT,
                                                 u32* __restrict__ bits) {
    const int bid = blockIdx.x;
    const int t = threadIdx.x;
    if (bid < 8192) {
        const int lane = t & 63;
        const size_t e0 = ((size_t)bid * 256 + t) * 4;
        const int4 v = *reinterpret_cast<const int4*>(adj + e0);
        u32 x = (v.x ? 1u : 0u) | (v.y ? 2u : 0u) | (v.z ? 4u : 0u) | (v.w ? 8u : 0u);
        {   const u32 r = (u32)__shfl_xor((int)x, 1);
            const int sh = (lane & 1) * 4;  x = (x << sh) | (r << (4 - sh)); }
        {   const u32 r = (u32)__shfl_xor((int)x, 2);
            const int sh = (lane & 2) * 4;  x = (x << sh) | (r << (8 - sh)); }
        {   const u32 r = (u32)__shfl_xor((int)x, 4);
            const int sh = (lane & 4) * 4;  x = (x << sh) | (r << (16 - sh)); }
        if ((lane & 7) == 0) bits[e0 >> 5] = x;
    } else if (bid < 9216) {
        const int i = ((bid - 8192) * 256 + t) * 8;
        const float4 v0 = *reinterpret_cast<const float4*>(h + i);
        const float4 v1 = *reinterpret_cast<const float4*>(h + i + 4);
        u16x8v o;
        o[0]=f2b(v0.x); o[1]=f2b(v0.y); o[2]=f2b(v0.z); o[3]=f2b(v0.w);
        o[4]=f2b(v1.x); o[5]=f2b(v1.y); o[6]=f2b(v1.z); o[7]=f2b(v1.w);
        *reinterpret_cast<u16x8v*>(hb + i) = o;
    } else {
        __shared__ float T[64][65];
        const int bb = bid - 9216;
        const int hh = bb & 7;
        const int n0 = hh * 64, k0 = (bb >> 3) * 64;
        const int r4 = t >> 6, c = t & 63;
        #pragma unroll
        for (int p = 0; p < 16; ++p) {
            const int r = p * 4 + r4;
            T[r][c] = W[(size_t)(k0 + r) * NH + n0 + c];
        }
        __syncthreads();
        #pragma unroll
        for (int p = 0; p < 16; ++p) {
            const int r = p * 4 + r4;
            WbT[(size_t)(n0 + r) * FIN + k0 + c] = f2b(T[c][r]);
        }
    }
}

// ---------------------------------------------------------------------------
// gemm_whT: Wh = hb @ WbT^T, 64x64 tile, grid 1024, XCD-chunked.
// Epilogue: exact-f32 e_src/e_dst from accumulators + transposed bf16 WhT.
// ---------------------------------------------------------------------------
__global__ __launch_bounds__(256) void gemm_whT(const u16* __restrict__ hb,
                                                const u16* __restrict__ WbT,
                                                const float* __restrict__ avec,
                                                u16* __restrict__ WhT,
                                                float* __restrict__ esrc,
                                                float* __restrict__ edst) {
    __shared__ u16 Al[2][64 * 64];
    __shared__ u16 Bl[2][64 * 64];
    const int t = threadIdx.x, wv = t >> 6, lane = t & 63;
    const int g = lane >> 4, l15 = lane & 15;
    const int lid = (blockIdx.x & 7) * 128 + (blockIdx.x >> 3);
    const int m0 = (lid >> 3) * 64;
    const int h  = lid & 7;
    const int lr = lane >> 3;
    const int sch = (lane & 7) ^ lr;
    const int bh = (m0 >> 10) * HEADS + h;

    f32x4 acc[4] = {};

    auto stageA = [&](int buf, int k0) {
        #pragma unroll
        for (int c = 0; c < 2; ++c) {
            const int rowb = wv * 16 + c * 8;
            gload_lds16(hb + (size_t)(m0 + rowb + lr) * FIN + k0 + sch * 8,
                        &Al[buf][rowb * 64]);
        }
    };
    auto stageB = [&](int buf, int k0) {
        #pragma unroll
        for (int c = 0; c < 2; ++c) {
            const int rowb = wv * 16 + c * 8;
            gload_lds16(WbT + (size_t)(h * 64 + rowb + lr) * FIN + k0 + sch * 8,
                        &Bl[buf][rowb * 64]);
        }
    };

    stageA(0, 0); stageB(0, 0);
    __syncthreads();
    for (int kt = 0; kt < 4; ++kt) {
        const int buf = kt & 1;
        if (kt < 3) { stageA(buf ^ 1, (kt + 1) * 64); stageB(buf ^ 1, (kt + 1) * 64); }
        #pragma unroll
        for (int ks = 0; ks < 2; ++ks) {
            const int ch = (ks * 4 + g) ^ (l15 & 7);
            const bf16x8 afr = *reinterpret_cast<const bf16x8*>(
                &Al[buf][(wv * 16 + l15) * 64 + ch * 8]);
            #pragma unroll
            for (int n = 0; n < 4; ++n) {
                const bf16x8 bfr = *reinterpret_cast<const bf16x8*>(
                    &Bl[buf][(n * 16 + l15) * 64 + ch * 8]);
                acc[n] = __builtin_amdgcn_mfma_f32_16x16x32_bf16(afr, bfr, acc[n], 0, 0, 0);
            }
        }
        __syncthreads();
    }

    // ---- e epilogue (exact f32, exp2 domain) ----
    {
        float as_[4], ad_[4];
        #pragma unroll
        for (int n = 0; n < 4; ++n) {
            as_[n] = avec[h * 128 + n * 16 + l15] * LOG2E;
            ad_[n] = avec[h * 128 + 64 + n * 16 + l15] * LOG2E;
        }
        #pragma unroll
        for (int r = 0; r < 4; ++r) {
            float ps = acc[0][r] * as_[0] + acc[1][r] * as_[1]
                     + acc[2][r] * as_[2] + acc[3][r] * as_[3];
            float pd = acc[0][r] * ad_[0] + acc[1][r] * ad_[1]
                     + acc[2][r] * ad_[2] + acc[3][r] * ad_[3];
            #pragma unroll
            for (int off = 1; off < 16; off <<= 1) {
                ps += __shfl_xor(ps, off);
                pd += __shfl_xor(pd, off);
            }
            if (l15 == 0) {
                const int i = (m0 + wv * 16 + g * 4 + r) & (NN - 1);
                esrc[(size_t)bh * NN + i] = ps;
                edst[(size_t)bh * NN + i] = pd;
            }
        }
    }

    // ---- WhT store via LDS bounce (coalesced) ----
    u16* scr = &Al[0][0];
    #pragma unroll
    for (int n = 0; n < 4; ++n) {
        u16x4v pk;
        #pragma unroll
        for (int r = 0; r < 4; ++r) pk[r] = f2b(acc[n][r]);
        *reinterpret_cast<u16x4v*>(&scr[(n * 16 + l15) * 72 + wv * 16 + g * 4]) = pk;
    }
    __syncthreads();
    const int il0 = m0 & (NN - 1);
    const int f = t >> 2, q = t & 3;
    const u16x8v v0 = *reinterpret_cast<const u16x8v*>(&scr[f * 72 + q * 16]);
    const u16x8v v1 = *reinterpret_cast<const u16x8v*>(&scr[f * 72 + q * 16 + 8]);
    u16* dst = &WhT[((size_t)bh * 64 + f) * NN + il0 + q * 16];
    *reinterpret_cast<u16x8v*>(dst)     = v0;
    *reinterpret_cast<u16x8v*>(dst + 8) = v1;
}

// ---------------------------------------------------------------------------
// attn_pv v12: r11 structure exactly (256 thr / 4 waves / 128 rows, dual-A,
// 16KB dbuf, grid 512, vmcnt(8) counted barrier, setprio, dsum via MFMA)
// + packed-f32 p-gen: add/lrelu in float2 ext-vectors -> v_pk_{add,mul,max}.
// ---------------------------------------------------------------------------
__global__ __launch_bounds__(256, 2) void attn_pv(const u32* __restrict__ bits,
                                                  const u16* __restrict__ WhT,
                                                  const float* __restrict__ esrc,
                                                  const float* __restrict__ edst,
                                                  float* __restrict__ out) {
    __shared__ u16 Bs[2][64 * 64];             // 16 KB, V tile dbuf
    const int t = threadIdx.x, wv = t >> 6, lane = t & 63;
    const int g = lane >> 4, l15 = lane & 15;
    const int lr = lane >> 3, sch = (lane & 7) ^ lr;

    // XCD chunk: 64 consecutive lids (8 i-chunks x 8 heads of one batch)/XCD
    const int lid = (blockIdx.x & 7) * 64 + (blockIdx.x >> 3);
    const int it = lid & 7, h = (lid >> 3) & 7, b = lid >> 6;
    const int i0 = it * 128;
    const int bh = b * HEADS + h;
    const int row0 = i0 + wv * 32 + l15;       // mf=0 row; mf=1 at +16

    const float es0 = esrc[(size_t)bh * NN + row0];
    const float es1 = esrc[(size_t)bh * NN + row0 + 16];
    const f32x2 es0v = {es0, es0};
    const f32x2 es1v = {es1, es1};
    const u16*  whb = WhT + (size_t)bh * 64 * NN;
    const float* ed = edst + (size_t)bh * NN + 8 * g;
    const u32*  bitrow0 = bits + (size_t)(b * NN + row0) * 32;
    const u32*  bitrow1 = bitrow0 + 16 * 32;

    auto stage = [&](int buf, int j0) {
        #pragma unroll
        for (int c = 0; c < 2; ++c) {
            const int fb = wv * 16 + c * 8;
            gload_lds16(whb + (size_t)(fb + lr) * NN + j0 + sch * 8,
                        &Bs[buf][fb * 64]);
        }
    };

    stage(0, 0);
    // 2-deep register prefetch slots (slot = parity of step s)
    float4 peA[2], peB[2];
    u32    pw0[2], pw1[2];
    #pragma unroll
    for (int s = 0; s < 2; ++s) {
        peA[s] = *(const float4*)(ed + s * 32);
        peB[s] = *(const float4*)(ed + s * 32 + 4);
        pw0[s] = bitrow0[s];
        pw1[s] = bitrow1[s];
    }
    __syncthreads();

    f32x4 acc0[4] = {}, acc1[4] = {};
    f32x4 dsum0 = {}, dsum1 = {};
    bf16x8 ones;
    #pragma unroll
    for (int q = 0; q < 8; ++q) ones[q] = (short)0x3F80;   // bf16(1.0)

    for (int tt = 0; tt < 16; ++tt) {
        const int buf = tt & 1;
        const bool more = (tt < 15);
        if (more) {
            stage(buf ^ 1, (tt + 1) * 64);
            asm volatile("" ::: "memory");     // pin: prefetches stay after stage
        }
        #pragma unroll
        for (int ks = 0; ks < 2; ++ks) {
            const int s = tt * 2 + ks;
            const float4 e0 = peA[ks], e1 = peB[ks];
            const u32 w0 = pw0[ks], w1 = pw1[ks];
            if (more) {                        // refill slot with step s+2
                peA[ks] = *(const float4*)(ed + (s + 2) * 32);
                peB[ks] = *(const float4*)(ed + (s + 2) * 32 + 4);
                pw0[ks] = bitrow0[s + 2];
                pw1[ks] = bitrow1[s + 2];
            }
            // B fragments early: ds latency hides under p-gen
            const int chb = ((ks * 4 + g) ^ (l15 & 7)) * 8;
            const bf16x8 v0 = *(const bf16x8*)(&Bs[buf][(0 * 16 + l15) * 64 + chb]);
            const bf16x8 v1 = *(const bf16x8*)(&Bs[buf][(1 * 16 + l15) * 64 + chb]);
            const bf16x8 v2 = *(const bf16x8*)(&Bs[buf][(2 * 16 + l15) * 64 + chb]);
            const bf16x8 v3 = *(const bf16x8*)(&Bs[buf][(3 * 16 + l15) * 64 + chb]);

            f32x2 ej2[4];
            ej2[0] = f32x2{e0.x, e0.y};
            ej2[1] = f32x2{e0.z, e0.w};
            ej2[2] = f32x2{e1.x, e1.y};
            ej2[3] = f32x2{e1.z, e1.w};
            const u32 by0 = (w0 >> (8 * g)) & 0xffu;
            const u32 by1 = (w1 >> (8 * g)) & 0xffu;

            union { u32 u[4]; bf16x8 v; } af0, af1;
            #pragma unroll
            for (int qp = 0; qp < 4; ++qp) {
                // packed add + lrelu (v_pk_add_f32 / v_pk_mul_f32 / v_pk_max_f32)
                f32x2 s0 = es0v + ej2[qp];
                f32x2 s1 = es1v + ej2[qp];
                s0 = __builtin_elementwise_max(s0, s0 * ALPHA);
                s1 = __builtin_elementwise_max(s1, s1 * ALPHA);
                const float p0a = fexp2(((by0 >> (2*qp))     & 1u) ? s0[0] : -1e30f);
                const float p0b = fexp2(((by0 >> (2*qp + 1)) & 1u) ? s0[1] : -1e30f);
                const float p1a = fexp2(((by1 >> (2*qp))     & 1u) ? s1[0] : -1e30f);
                const float p1b = fexp2(((by1 >> (2*qp + 1)) & 1u) ? s1[1] : -1e30f);
                union { __hip_bfloat162 b2; u32 w; } c0, c1;
                c0.b2 = __float22bfloat162_rn(make_float2(p0a, p0b));
                c1.b2 = __float22bfloat162_rn(make_float2(p1a, p1b));
                af0.u[qp] = c0.w;
                af1.u[qp] = c1.w;
            }
            __builtin_amdgcn_s_setprio(1);
            acc0[0] = __builtin_amdgcn_mfma_f32_16x16x32_bf16(af0.v, v0, acc0[0], 0, 0, 0);
            acc1[0] = __builtin_amdgcn_mfma_f32_16x16x32_bf16(af1.v, v0, acc1[0], 0, 0, 0);
            acc0[1] = __builtin_amdgcn_mfma_f32_16x16x32_bf16(af0.v, v1, acc0[1], 0, 0, 0);
            acc1[1] = __builtin_amdgcn_mfma_f32_16x16x32_bf16(af1.v, v1, acc1[1], 0, 0, 0);
            acc0[2] = __builtin_amdgcn_mfma_f32_16x16x32_bf16(af0.v, v2, acc0[2], 0, 0, 0);
            acc1[2] = __builtin_amdgcn_mfma_f32_16x16x32_bf16(af1.v, v2, acc1[2], 0, 0, 0);
            acc0[3] = __builtin_amdgcn_mfma_f32_16x16x32_bf16(af0.v, v3, acc0[3], 0, 0, 0);
            acc1[3] = __builtin_amdgcn_mfma_f32_16x16x32_bf16(af1.v, v3, acc1[3], 0, 0, 0);
            dsum0   = __builtin_amdgcn_mfma_f32_16x16x32_bf16(af0.v, ones, dsum0, 0, 0, 0);
            dsum1   = __builtin_amdgcn_mfma_f32_16x16x32_bf16(af1.v, ones, dsum1, 0, 0, 0);
            __builtin_amdgcn_s_setprio(0);
        }
        if (more) {
            // per-wave VMEM newer than the last stage load: 8 prefetches
            // -> vmcnt(8) guarantees stage landed, prefetches stay in flight.
            asm volatile("s_waitcnt vmcnt(8)" ::: "memory");
            __builtin_amdgcn_s_barrier();
        }
    }

    float inv0[4], inv1[4];
    #pragma unroll
    for (int r = 0; r < 4; ++r) { inv0[r] = 1.0f / dsum0[r]; inv1[r] = 1.0f / dsum1[r]; }
    #pragma unroll
    for (int n = 0; n < 4; ++n)
        #pragma unroll
        for (int r = 0; r < 4; ++r) {
            const int io0 = i0 + wv * 32 + g * 4 + r;
            out[(size_t)(b * NN + io0) * NH + h * 64 + n * 16 + l15] =
                acc0[n][r] * inv0[r];
            out[(size_t)(b * NN + io0 + 16) * NH + h * 64 + n * 16 + l15] =
                acc1[n][r] * inv1[r];
        }
}

// ---------------------------------------------------------------------------
extern "C" void kernel_launch(void* const* d_in, const int* in_sizes, int n_in,
                              void* d_out, int out_size, void* d_ws, size_t ws_size,
                              hipStream_t stream) {
    const float* h   = (const float*)d_in[0];
    const int*   adj = (const int*)  d_in[1];
    const float* W   = (const float*)d_in[2];
    const float* a   = (const float*)d_in[3];
    float* out = (float*)d_out;

    char* p = (char*)d_ws;
    u16*   hb   = (u16*)p;   p += (size_t)BS * NN * FIN * 2;        // 4 MB
    u16*   WbT  = (u16*)p;   p += (size_t)NH * FIN * 2;             // 256 KB
    u16*   WhT  = (u16*)p;   p += (size_t)BS * HEADS * FO * NN * 2; // 8 MB
    float* esrc = (float*)p; p += (size_t)BS * HEADS * NN * 4;      // 256 KB
    float* edst = (float*)p; p += (size_t)BS * HEADS * NN * 4;      // 256 KB
    u32*   bits = (u32*)p;                                          // 1 MB

    prep_misc<<<9248, 256, 0, stream>>>(h, adj, W, hb, WbT, bits);
    gemm_whT <<<1024, 256, 0, stream>>>(hb, WbT, a, WhT, esrc, edst);
    attn_pv  <<<512, 256, 0, stream>>>(bits, WhT, esrc, edst, out);
}